// Round 5
// baseline (676.742 us; speedup 1.0000x reference)
//
#include <hip/hip_runtime.h>
#include <math.h>

#define LL 256
#define DD 768
#define HH 384
#define G4 1536
#define NWIN 4
#define NLIN 9
#define NPOS 1024        // B*L
#define PROJ_N 12288     // 8 chains * 1536

typedef __attribute__((ext_vector_type(8))) short short8;
typedef __attribute__((ext_vector_type(16))) float f32x16;

static __device__ __forceinline__ float bf2f(unsigned short u) {
    union { unsigned int i; float f; } v; v.i = ((unsigned int)u) << 16; return v.f;
}
static __device__ __forceinline__ unsigned short f2bf(float f) {
    unsigned int u = __float_as_uint(f);
    u += 0x7fff + ((u >> 16) & 1);   // round-to-nearest-even
    return (unsigned short)(u >> 16);
}

// ---------------------------------------------------------------- zero
__global__ void zero_f4(float4* __restrict__ p, int n4) {
    int i = blockIdx.x * blockDim.x + threadIdx.x;
    if (i < n4) p[i] = make_float4(0.f, 0.f, 0.f, 0.f);
}

// ---------------------------------------------------------------- scatter
// x[b, dest[l], :] = seq[b, l, :] ; also writes bf16 MFMA-A-fragment layout:
// xfrag[pt][ks][lane][8], lane = (pos&31) + 32*khalf, k = ks*16 + khalf*8 + j
__global__ void scatter_kernel(const float* __restrict__ seq,
                               const int* __restrict__ valid,
                               float* __restrict__ x,
                               unsigned short* __restrict__ xfrag) {
    const int b = blockIdx.x >> 5;
    const int chunk = blockIdx.x & 31;
    const int tid = threadIdx.x;
    __shared__ int vbuf[LL];
    __shared__ int dest[LL];
    vbuf[tid] = valid[b * LL + tid];
    __syncthreads();
    if (tid == 0) {
        int c = 0;
        for (int l = 0; l < LL; ++l) dest[l] = vbuf[l] ? c++ : -1;
    }
    __syncthreads();
    for (int l = chunk * 8; l < chunk * 8 + 8; ++l) {
        const int d = dest[l];
        if (d >= 0) {
            const float* src = seq + (size_t)(b * LL + l) * DD;
            float* dst = x + (size_t)(b * LL + d) * DD;
            for (int j = tid; j < DD / 4; j += 256)
                ((float4*)dst)[j] = ((const float4*)src)[j];
            const int pos = b * LL + d;
            const int pt = pos >> 5, pl = pos & 31;
            for (int j = tid; j < DD / 8; j += 256) {
                const float4 v0 = ((const float4*)src)[2 * j];
                const float4 v1 = ((const float4*)src)[2 * j + 1];
                short8 pv;
                pv[0] = (short)f2bf(v0.x); pv[1] = (short)f2bf(v0.y);
                pv[2] = (short)f2bf(v0.z); pv[3] = (short)f2bf(v0.w);
                pv[4] = (short)f2bf(v1.x); pv[5] = (short)f2bf(v1.y);
                pv[6] = (short)f2bf(v1.z); pv[7] = (short)f2bf(v1.w);
                *(short8*)(xfrag + ((size_t)(pt * 48 + (j >> 1)) * 512 + (pl + 32 * (j & 1)) * 8)) = pv;
            }
        }
    }
}

// ---------------------------------------------------------------- cast weights -> B-fragment layout
__global__ __launch_bounds__(256) void cast_frag(
        const float* __restrict__ srcF, const float* __restrict__ srcB,
        unsigned short* __restrict__ dst, int K) {
    __shared__ unsigned short lds[32 * 768];
    const int tid = threadIdx.x;
    const int vrow0 = blockIdx.x * 32;
    const int chain = vrow0 / G4;
    const int dir = chain >> 2, wi = chain & 3;
    const float* src = (dir ? srcB : srcF) + (size_t)(wi * G4 + (vrow0 % G4)) * K;
    const int total = 32 * K;
    for (int i = tid * 4; i < total; i += 1024) {
        const float4 v = *(const float4*)(src + i);
        lds[i + 0] = f2bf(v.x); lds[i + 1] = f2bf(v.y);
        lds[i + 2] = f2bf(v.z); lds[i + 3] = f2bf(v.w);
    }
    __syncthreads();
    const int nks = K >> 4;
    for (int slot = tid; slot < nks * 64; slot += 256) {
        const int ks = slot >> 6;
        const int lane = slot & 63;
        const int row = lane & 31;
        const int kb = ks * 16 + (lane >> 5) * 8;
        const short8 v = *(const short8*)&lds[row * K + kb];
        *(short8*)(dst + ((size_t)blockIdx.x * nks + ks) * 512 + lane * 8) = v;
    }
}

// ---------------------------------------------------------------- combined bias
__global__ void bias_kernel(const float* __restrict__ bihf, const float* __restrict__ bhhf,
                            const float* __restrict__ bihb, const float* __restrict__ bhhb,
                            float* __restrict__ bias) {
    const int n = blockIdx.x * 256 + threadIdx.x;
    if (n >= PROJ_N) return;
    const int chain = n / G4, r = n % G4;
    const int dir = chain >> 2, wi = chain & 3;
    bias[n] = (dir ? bihb : bihf)[wi * G4 + r] + (dir ? bhhb : bhhf)[wi * G4 + r];
}

// ---------------------------------------------------------------- proj GEMM (MFMA, frag-direct)
// Wave computes 32 pos x 64 n. Block = 4 waves, SAME ng (B shared via L1),
// consecutive mt. Output: linear proj[pos][chain*1536 + g*384 + u] (dense 64B
// lane-runs, both halves of each 128B line written by the same wave -> no
// write amplification).
__global__ __launch_bounds__(256) void proj_mfma(
        const unsigned short* __restrict__ xf,
        const unsigned short* __restrict__ wf,
        const float* __restrict__ bias,
        unsigned short* __restrict__ proj) {
    const int wv = threadIdx.x >> 6;
    const int lane = threadIdx.x & 63;
    const int colid = lane & 31, hq = lane >> 5;
    const int mtg = blockIdx.x / 192;       // 0..7
    const int ng  = blockIdx.x % 192;       // 0..191
    const int mt  = mtg * 4 + wv;           // 0..31
    const unsigned short* aP = xf + (size_t)(mt * 48) * 512 + lane * 8;
    const unsigned short* bP = wf + (size_t)(ng * 2 * 48) * 512 + lane * 8;

    f32x16 acc0 = {}, acc1 = {};
#pragma unroll 4
    for (int ks = 0; ks < 48; ++ks) {
        const short8 a  = *(const short8*)(aP + ks * 512);
        const short8 b0 = *(const short8*)(bP + ks * 512);
        const short8 b1 = *(const short8*)(bP + (48 + ks) * 512);
        acc0 = __builtin_amdgcn_mfma_f32_32x32x16_bf16(a, b0, acc0, 0, 0, 0);
        acc1 = __builtin_amdgcn_mfma_f32_32x32x16_bf16(a, b1, acc1, 0, 0, 0);
    }
#pragma unroll
    for (int jj = 0; jj < 2; ++jj) {
        const int gv = ng * 64 + jj * 32 + colid;
        const float bv = bias[gv];
        const f32x16& a = jj ? acc1 : acc0;
#pragma unroll
        for (int r16 = 0; r16 < 16; ++r16) {
            const int row = (r16 & 3) + 8 * (r16 >> 2) + 4 * hq;
            const int pos = mt * 32 + row;
            proj[(size_t)pos * PROJ_N + gv] = f2bf(a[r16] + bv);
        }
    }
}

// ---------------------------------------------------------------- fused LSTM recurrence
// One block per (chain, 32-pos tile): 256 blocks, 768 thr = 12 waves.
// chain = blockIdx&7 -> XCD pin: chain's W_hh slice (1.18 MB) stays in that
// XCD's L2. Wave wv owns units [wv*32, +32), all 4 gates. All w steps run
// in-kernel: H in LDS (A-frag layout), C in registers, 2 barriers/step.
__global__ __launch_bounds__(768) void lstm_fused(
        const unsigned short* __restrict__ Wf,
        const unsigned short* __restrict__ proj,
        unsigned short* __restrict__ hfin) {
    const int chain = blockIdx.x & 7;
    const int pt = blockIdx.x >> 3;
    const int dir = chain >> 2, wi = chain & 3;
    const int w = 3 + 2 * wi, half = wi + 1;
    const int tid = threadIdx.x;
    const int lane = tid & 63, wv = tid >> 6;   // wv 0..11
    const int colid = lane & 31, hq = lane >> 5;
    const int uu = wv * 32 + colid;
    const int m0 = pt * 32, b = m0 >> 8, l0 = m0 & 255;

    __shared__ __align__(16) unsigned short Hlds[24 * 512];   // 24 KB
    ((int4*)Hlds)[tid] = make_int4(0, 0, 0, 0);
    ((int4*)Hlds)[tid + 768] = make_int4(0, 0, 0, 0);
    float c[16];
#pragma unroll
    for (int r = 0; r < 16; ++r) c[r] = 0.f;

    const unsigned short* projb = proj + (size_t)b * LL * PROJ_N + chain * G4 + uu;
    // W B-frag base for (chain, gate g, unit-slice wv): tile = chain*48 + g*12 + wv
    const unsigned short* Wb = Wf + (size_t)((chain * 48 + wv) * 24) * 512 + lane * 8;

    __syncthreads();

    for (int s = 0; s < w; ++s) {
        const int t = dir ? (w - 1 - s) : s;
        // ---- A-frags from LDS (all 384 k of H for this pos tile)
        short8 a[24];
#pragma unroll
        for (int ks = 0; ks < 24; ++ks)
            a[ks] = *(const short8*)&Hlds[ks * 512 + lane * 8];
        // ---- proj prefetch (global, overlaps barrier + MFMAs)
        unsigned short pjv[4][16];
        bool vld[16];
#pragma unroll
        for (int r = 0; r < 16; ++r) {
            const int row = (r & 3) + 8 * (r >> 2) + 4 * hq;
            const int src = l0 + row + t - half;
            vld[r] = (src >= 0) && (src < LL);
            const int srcc = src < 0 ? 0 : (src > LL - 1 ? LL - 1 : src);
            const unsigned short* pp = projb + (size_t)srcc * PROJ_N;
            pjv[0][r] = pp[0];
            pjv[1][r] = pp[HH];
            pjv[2][r] = pp[2 * HH];
            pjv[3][r] = pp[3 * HH];
        }
        __syncthreads();   // all LDS reads of step s complete

        f32x16 acc0 = {}, acc1 = {}, acc2 = {}, acc3 = {};
#pragma unroll 4
        for (int ks = 0; ks < 24; ++ks) {
            const short8 bv0 = *(const short8*)(Wb + (size_t)(0 * 288 + ks) * 512);
            const short8 bv1 = *(const short8*)(Wb + (size_t)(1 * 288 + ks) * 512);
            const short8 bv2 = *(const short8*)(Wb + (size_t)(2 * 288 + ks) * 512);
            const short8 bv3 = *(const short8*)(Wb + (size_t)(3 * 288 + ks) * 512);
            acc0 = __builtin_amdgcn_mfma_f32_32x32x16_bf16(a[ks], bv0, acc0, 0, 0, 0);
            acc1 = __builtin_amdgcn_mfma_f32_32x32x16_bf16(a[ks], bv1, acc1, 0, 0, 0);
            acc2 = __builtin_amdgcn_mfma_f32_32x32x16_bf16(a[ks], bv2, acc2, 0, 0, 0);
            acc3 = __builtin_amdgcn_mfma_f32_32x32x16_bf16(a[ks], bv3, acc3, 0, 0, 0);
        }

        // ---- cell update + H write (disjoint per-wave LDS region)
        const int ksp = uu >> 4, khp = (uu >> 3) & 1, jp = uu & 7;
#pragma unroll
        for (int r = 0; r < 16; ++r) {
            if (vld[r]) {
                const int row = (r & 3) + 8 * (r >> 2) + 4 * hq;
                const float gi = acc0[r] + bf2f(pjv[0][r]);
                const float gf = acc1[r] + bf2f(pjv[1][r]);
                const float gg = acc2[r] + bf2f(pjv[2][r]);
                const float go = acc3[r] + bf2f(pjv[3][r]);
                const float iv = 1.f / (1.f + __expf(-gi));
                const float fv = 1.f / (1.f + __expf(-gf));
                const float gv = tanhf(gg);
                const float ov = 1.f / (1.f + __expf(-go));
                c[r] = fv * c[r] + iv * gv;
                Hlds[ksp * 512 + (row + 32 * khp) * 8 + jp] = f2bf(ov * tanhf(c[r]));
            }
        }
        __syncthreads();   // writes visible before next step's reads
    }

    // ---- final H -> global (hfrag layout, same as LDS layout per pos-tile)
    unsigned short* ho = hfin + (size_t)chain * (NPOS * HH) + (size_t)pt * 12288;
    ((int4*)ho)[tid] = ((const int4*)Hlds)[tid];
    ((int4*)ho)[tid + 768] = ((const int4*)Hlds)[tid + 768];
}

// ---------------------------------------------------------------- attention + linear head
static __device__ __forceinline__ float hfrag_get(const unsigned short* __restrict__ h,
                                                  int chain, int P, int c) {
    const size_t idx = (size_t)chain * (NPOS * HH)
        + (size_t)((P >> 5) * 24 + (c >> 4)) * 512
        + ((P & 31) + 32 * ((c >> 3) & 1)) * 8 + (c & 7);
    return bf2f(h[idx]);
}

__global__ __launch_bounds__(256) void attn_out_kernel(
        const float* __restrict__ x, const unsigned short* __restrict__ hout,
        const float* __restrict__ lin_w, const float* __restrict__ lin_b,
        float* __restrict__ out) {
    const int P = blockIdx.x;
    const int tid = threadIdx.x;
    const int lane = tid & 63, wid = tid >> 6;
    __shared__ float sc[NWIN][4];
    __shared__ float attn_s[NWIN];
    __shared__ float ov[DD];
    __shared__ float red[NLIN][4];
    const float inv_sqrt_d = 0.03608439182435161f;

    float xr[3];
#pragma unroll
    for (int j = 0; j < 3; ++j) xr[j] = x[(size_t)P * DD + tid + 256 * j];

#pragma unroll
    for (int wi = 0; wi < NWIN; ++wi) {
        float part = 0.f;
#pragma unroll
        for (int j = 0; j < 3; ++j) {
            const int col = tid + 256 * j;
            const float m = (col < HH) ? hfrag_get(hout, wi, P, col)
                                       : hfrag_get(hout, 4 + wi, P, col - HH);
            part = fmaf(xr[j], m, part);
        }
        for (int off = 32; off > 0; off >>= 1) part += __shfl_down(part, off);
        if (lane == 0) sc[wi][wid] = part;
    }
    __syncthreads();
    if (tid == 0) {
        float s[NWIN], mx = -1e30f;
        for (int wi = 0; wi < NWIN; ++wi) {
            s[wi] = (sc[wi][0] + sc[wi][1] + sc[wi][2] + sc[wi][3]) * inv_sqrt_d;
            mx = fmaxf(mx, s[wi]);
        }
        float denom = 0.f;
        for (int wi = 0; wi < NWIN; ++wi) { s[wi] = __expf(s[wi] - mx); denom += s[wi]; }
        for (int wi = 0; wi < NWIN; ++wi) attn_s[wi] = s[wi] / denom;
    }
    __syncthreads();
#pragma unroll
    for (int j = 0; j < 3; ++j) {
        const int col = tid + 256 * j;
        float lv = 0.f;
#pragma unroll
        for (int wi = 0; wi < NWIN; ++wi) {
            const float m = (col < HH) ? hfrag_get(hout, wi, P, col)
                                       : hfrag_get(hout, 4 + wi, P, col - HH);
            lv = fmaf(attn_s[wi], m, lv);
        }
        ov[col] = xr[j] + lv;
    }
    __syncthreads();
    for (int r = 0; r < NLIN; ++r) {
        float part = 0.f;
#pragma unroll
        for (int j = 0; j < 3; ++j) {
            const int col = tid + 256 * j;
            part = fmaf(ov[col], lin_w[r * DD + col], part);
        }
        for (int off = 32; off > 0; off >>= 1) part += __shfl_down(part, off);
        if (lane == 0) red[r][wid] = part;
    }
    __syncthreads();
    if (tid < NLIN)
        out[(size_t)P * NLIN + tid] = red[tid][0] + red[tid][1] + red[tid][2] + red[tid][3] + lin_b[tid];
}

// ---------------------------------------------------------------- launch
extern "C" void kernel_launch(void* const* d_in, const int* in_sizes, int n_in,
                              void* d_out, int out_size, void* d_ws, size_t ws_size,
                              hipStream_t stream) {
    (void)in_sizes; (void)n_in; (void)out_size; (void)ws_size;
    const float* seq   = (const float*)d_in[0];
    const int*   valid = (const int*)d_in[1];
    const float* wih_f = (const float*)d_in[2];
    const float* whh_f = (const float*)d_in[3];
    const float* bih_f = (const float*)d_in[4];
    const float* bhh_f = (const float*)d_in[5];
    const float* wih_b = (const float*)d_in[6];
    const float* whh_b = (const float*)d_in[7];
    const float* bih_b = (const float*)d_in[8];
    const float* bhh_b = (const float*)d_in[9];
    const float* lin_w = (const float*)d_in[10];
    const float* lin_b = (const float*)d_in[11];
    float* out = (float*)d_out;

    // workspace layout (~64.5 MB)
    float*          x     = (float*)d_ws;                          // 786432 f32
    unsigned short* xfrag = (unsigned short*)(x + NPOS * DD);      // 786432 bf16
    unsigned short* proj  = xfrag + (size_t)NPOS * DD;             // 12582912 bf16
    unsigned short* wfhh  = proj + (size_t)NPOS * PROJ_N;          // 4718592 bf16
    unsigned short* wfih  = wfhh + (size_t)4718592;                // 9437184 bf16
    unsigned short* hfin  = wfih + (size_t)9437184;                // 3145728 bf16
    float*          bias  = (float*)(hfin + (size_t)8 * NPOS * HH);// 12288 f32

    // x + xfrag contiguous: one zero launch (4718592 B = 294912 float4)
    zero_f4<<<(294912 + 255) / 256, 256, 0, stream>>>((float4*)x, 294912);
    scatter_kernel<<<128, 256, 0, stream>>>(seq, valid, x, xfrag);
    cast_frag<<<384, 256, 0, stream>>>(wih_f, wih_b, wfih, DD);
    cast_frag<<<384, 256, 0, stream>>>(whh_f, whh_b, wfhh, HH);
    bias_kernel<<<48, 256, 0, stream>>>(bih_f, bhh_f, bih_b, bhh_b, bias);
    proj_mfma<<<1536, 256, 0, stream>>>(xfrag, wfih, bias, proj);
    lstm_fused<<<256, 768, 0, stream>>>(wfhh, proj, hfin);
    attn_out_kernel<<<NPOS, 256, 0, stream>>>(x, hfin, lin_w, lin_b, out);
}

// Round 6
// 380.118 us; speedup vs baseline: 1.7803x; 1.7803x over previous
//
#include <hip/hip_runtime.h>
#include <math.h>

#define LL 256
#define DD 768
#define HH 384
#define G4 1536
#define NWIN 4
#define NLIN 9
#define NPOS 1024        // B*L
#define PROJ_N 12288     // 8 chains * 1536

typedef __attribute__((ext_vector_type(8))) short short8;
typedef __attribute__((ext_vector_type(4))) short short4v;
typedef __attribute__((ext_vector_type(16))) float f32x16;

static __device__ __forceinline__ float bf2f(unsigned short u) {
    union { unsigned int i; float f; } v; v.i = ((unsigned int)u) << 16; return v.f;
}
static __device__ __forceinline__ unsigned short f2bf(float f) {
    unsigned int u = __float_as_uint(f);
    u += 0x7fff + ((u >> 16) & 1);   // round-to-nearest-even
    return (unsigned short)(u >> 16);
}

// ---------------------------------------------------------------- zero
__global__ void zero_f4(float4* __restrict__ p, int n4) {
    int i = blockIdx.x * blockDim.x + threadIdx.x;
    if (i < n4) p[i] = make_float4(0.f, 0.f, 0.f, 0.f);
}

// ---------------------------------------------------------------- scatter
// x[b, dest[l], :] = seq[b, l, :] ; also writes bf16 MFMA-A-fragment layout:
// xfrag[pt][ks][lane][8], lane = (pos&31) + 32*khalf, k = ks*16 + khalf*8 + j
__global__ void scatter_kernel(const float* __restrict__ seq,
                               const int* __restrict__ valid,
                               float* __restrict__ x,
                               unsigned short* __restrict__ xfrag) {
    const int b = blockIdx.x >> 5;
    const int chunk = blockIdx.x & 31;
    const int tid = threadIdx.x;
    __shared__ int vbuf[LL];
    __shared__ int dest[LL];
    vbuf[tid] = valid[b * LL + tid];
    __syncthreads();
    if (tid == 0) {
        int c = 0;
        for (int l = 0; l < LL; ++l) dest[l] = vbuf[l] ? c++ : -1;
    }
    __syncthreads();
    for (int l = chunk * 8; l < chunk * 8 + 8; ++l) {
        const int d = dest[l];
        if (d >= 0) {
            const float* src = seq + (size_t)(b * LL + l) * DD;
            float* dst = x + (size_t)(b * LL + d) * DD;
            for (int j = tid; j < DD / 4; j += 256)
                ((float4*)dst)[j] = ((const float4*)src)[j];
            const int pos = b * LL + d;
            const int pt = pos >> 5, pl = pos & 31;
            for (int j = tid; j < DD / 8; j += 256) {
                const float4 v0 = ((const float4*)src)[2 * j];
                const float4 v1 = ((const float4*)src)[2 * j + 1];
                short8 pv;
                pv[0] = (short)f2bf(v0.x); pv[1] = (short)f2bf(v0.y);
                pv[2] = (short)f2bf(v0.z); pv[3] = (short)f2bf(v0.w);
                pv[4] = (short)f2bf(v1.x); pv[5] = (short)f2bf(v1.y);
                pv[6] = (short)f2bf(v1.z); pv[7] = (short)f2bf(v1.w);
                *(short8*)(xfrag + ((size_t)(pt * 48 + (j >> 1)) * 512 + (pl + 32 * (j & 1)) * 8)) = pv;
            }
        }
    }
}

// ---------------------------------------------------------------- cast weights -> B-fragment layout
__global__ __launch_bounds__(256) void cast_frag(
        const float* __restrict__ srcF, const float* __restrict__ srcB,
        unsigned short* __restrict__ dst, int K) {
    __shared__ unsigned short lds[32 * 768];
    const int tid = threadIdx.x;
    const int vrow0 = blockIdx.x * 32;
    const int chain = vrow0 / G4;
    const int dir = chain >> 2, wi = chain & 3;
    const float* src = (dir ? srcB : srcF) + (size_t)(wi * G4 + (vrow0 % G4)) * K;
    const int total = 32 * K;
    for (int i = tid * 4; i < total; i += 1024) {
        const float4 v = *(const float4*)(src + i);
        lds[i + 0] = f2bf(v.x); lds[i + 1] = f2bf(v.y);
        lds[i + 2] = f2bf(v.z); lds[i + 3] = f2bf(v.w);
    }
    __syncthreads();
    const int nks = K >> 4;
    for (int slot = tid; slot < nks * 64; slot += 256) {
        const int ks = slot >> 6;
        const int lane = slot & 63;
        const int row = lane & 31;
        const int kb = ks * 16 + (lane >> 5) * 8;
        const short8 v = *(const short8*)&lds[row * K + kb];
        *(short8*)(dst + ((size_t)blockIdx.x * nks + ks) * 512 + lane * 8) = v;
    }
}

// ---------------------------------------------------------------- combined bias
__global__ void bias_kernel(const float* __restrict__ bihf, const float* __restrict__ bhhf,
                            const float* __restrict__ bihb, const float* __restrict__ bhhb,
                            float* __restrict__ bias) {
    const int n = blockIdx.x * 256 + threadIdx.x;
    if (n >= PROJ_N) return;
    const int chain = n / G4, r = n % G4;
    const int dir = chain >> 2, wi = chain & 3;
    bias[n] = (dir ? bihb : bihf)[wi * G4 + r] + (dir ? bhhb : bhhf)[wi * G4 + r];
}

// ---------------------------------------------------------------- proj GEMM (MFMA)
// Block = (chain, us, mtg): 4 waves = 4 gates (share B per iter), each wave
// computes 4 mt tiles (32 pos each) for its gate over K=768.
// Output proj[pos][chain][u][gate] via LDS staging -> dense 256B/row stores.
__global__ __launch_bounds__(256) void proj_mfma(
        const unsigned short* __restrict__ xf,
        const unsigned short* __restrict__ wf,
        const float* __restrict__ bias,
        unsigned short* __restrict__ proj) {
    __shared__ __align__(16) unsigned short st[4 * 4096];   // 32 KB
    const int wv = threadIdx.x >> 6;        // gate
    const int lane = threadIdx.x & 63;
    const int colid = lane & 31, hq = lane >> 5;
    const int mtg = blockIdx.x & 7;
    const int cu = blockIdx.x >> 3;         // 0..95
    const int chain = cu / 12;
    const int us = cu % 12;

    const unsigned short* bP = wf + (size_t)((chain * 48 + wv * 12 + us) * 48) * 512 + lane * 8;
    const unsigned short* aP = xf + (size_t)(mtg * 4 * 48) * 512 + lane * 8;

    f32x16 acc[4] = {};
#pragma unroll 4
    for (int ks = 0; ks < 48; ++ks) {
        const short8 bv = *(const short8*)(bP + ks * 512);
        const short8 a0 = *(const short8*)(aP + (0 * 48 + ks) * 512);
        const short8 a1 = *(const short8*)(aP + (1 * 48 + ks) * 512);
        const short8 a2 = *(const short8*)(aP + (2 * 48 + ks) * 512);
        const short8 a3 = *(const short8*)(aP + (3 * 48 + ks) * 512);
        acc[0] = __builtin_amdgcn_mfma_f32_32x32x16_bf16(a0, bv, acc[0], 0, 0, 0);
        acc[1] = __builtin_amdgcn_mfma_f32_32x32x16_bf16(a1, bv, acc[1], 0, 0, 0);
        acc[2] = __builtin_amdgcn_mfma_f32_32x32x16_bf16(a2, bv, acc[2], 0, 0, 0);
        acc[3] = __builtin_amdgcn_mfma_f32_32x32x16_bf16(a3, bv, acc[3], 0, 0, 0);
    }
    const float bv = bias[chain * G4 + wv * HH + us * 32 + colid];
#pragma unroll
    for (int i = 0; i < 4; ++i) {
#pragma unroll
        for (int r = 0; r < 16; ++r) {
            const int row = (r & 3) + 8 * (r >> 2) + 4 * hq;
            st[i * 4096 + (row * 32 + colid) * 4 + wv] = f2bf(acc[i][r] + bv);
        }
    }
    __syncthreads();
#pragma unroll
    for (int j = 0; j < 8; ++j) {
        const int idx = j * 256 + threadIdx.x;    // 0..2047 int4
        const int i = idx >> 9, rem = idx & 511;
        const int pl = rem >> 4, q = rem & 15;
        const int pos = (mtg * 4 + i) * 32 + pl;
        *(int4*)(proj + (size_t)pos * PROJ_N + chain * G4 + us * 128 + q * 8) =
            ((const int4*)st)[idx];
    }
}

// ---------------------------------------------------------------- fused LSTM recurrence
// One block per (chain, 32-pos tile); 256 blocks = 1/CU; 768 thr = 12 waves.
// Chain-pair XCD mapping: XCDs {0,4}:{3,0} {1,5}:{7,4} {2,6}:{2,1} {3,7}:{6,5}
// balances per-XCD L2 W-traffic (both W slices = 2.4MB < 4MB L2).
// H in LDS (A-frag layout, ds_read in k-loop), C in regs, proj gate-packed.
__global__ __launch_bounds__(768, 3) void lstm_fused(
        const unsigned short* __restrict__ Wf,
        const unsigned short* __restrict__ proj,
        unsigned short* __restrict__ hfin) {
    const int p = blockIdx.x & 3, sub = (blockIdx.x >> 2) & 1;
    const int slot = blockIdx.x >> 3;
    const int chainA[4] = {3, 7, 2, 6};   // w=9,9,7,7
    const int chainB[4] = {0, 4, 1, 5};   // w=3,3,5,5
    const int chain = (slot < 16) ? chainA[p] : chainB[p];
    const int pt = sub * 16 + (slot & 15);
    const int dir = chain >> 2, wi = chain & 3;
    const int w = 3 + 2 * wi, half = wi + 1;
    const int tid = threadIdx.x;
    const int lane = tid & 63, wv = tid >> 6;   // wv 0..11 = unit slice
    const int colid = lane & 31, hq = lane >> 5;
    const int uu = wv * 32 + colid;
    const int m0 = pt * 32, b = m0 >> 8, l0 = m0 & 255;

    __shared__ __align__(16) unsigned short Hlds[24 * 512];   // 24 KB
    ((int4*)Hlds)[tid] = make_int4(0, 0, 0, 0);
    ((int4*)Hlds)[tid + 768] = make_int4(0, 0, 0, 0);
    float c[16];
#pragma unroll
    for (int r = 0; r < 16; ++r) c[r] = 0.f;

    const unsigned short* projb = proj + (size_t)b * LL * PROJ_N + chain * G4 + uu * 4;
    const unsigned short* Wb = Wf + (size_t)((chain * 48 + wv) * 24) * 512 + lane * 8;
    const unsigned short* Alds = Hlds + lane * 8;
    const int ksp = uu >> 4, khp = (uu >> 3) & 1, jp = uu & 7;

    __syncthreads();

    for (int s = 0; s < w; ++s) {
        const int t = dir ? (w - 1 - s) : s;
        // ---- gate-packed proj prefetch (independent of MFMAs)
        short4v pj[16];
#pragma unroll
        for (int r = 0; r < 16; ++r) {
            const int row = (r & 3) + 8 * (r >> 2) + 4 * hq;
            int src = l0 + row + t - half;
            src = src < 0 ? 0 : (src > LL - 1 ? LL - 1 : src);
            pj[r] = *(const short4v*)(projb + (size_t)src * PROJ_N);
        }
        f32x16 acc0 = {}, acc1 = {}, acc2 = {}, acc3 = {};
        if (s > 0) {   // s==0: H is zero, gates = proj only
#pragma unroll 4
            for (int ks = 0; ks < 24; ++ks) {
                const short8 av  = *(const short8*)(Alds + ks * 512);
                const short8 bv0 = *(const short8*)(Wb + (size_t)(0 * 288 + ks) * 512);
                const short8 bv1 = *(const short8*)(Wb + (size_t)(1 * 288 + ks) * 512);
                const short8 bv2 = *(const short8*)(Wb + (size_t)(2 * 288 + ks) * 512);
                const short8 bv3 = *(const short8*)(Wb + (size_t)(3 * 288 + ks) * 512);
                acc0 = __builtin_amdgcn_mfma_f32_32x32x16_bf16(av, bv0, acc0, 0, 0, 0);
                acc1 = __builtin_amdgcn_mfma_f32_32x32x16_bf16(av, bv1, acc1, 0, 0, 0);
                acc2 = __builtin_amdgcn_mfma_f32_32x32x16_bf16(av, bv2, acc2, 0, 0, 0);
                acc3 = __builtin_amdgcn_mfma_f32_32x32x16_bf16(av, bv3, acc3, 0, 0, 0);
            }
        }
        __syncthreads();   // all LDS reads of step s done

#pragma unroll
        for (int r = 0; r < 16; ++r) {
            const int row = (r & 3) + 8 * (r >> 2) + 4 * hq;
            const int src = l0 + row + t - half;
            if (src >= 0 && src < LL) {
                const float gi = acc0[r] + bf2f((unsigned short)pj[r][0]);
                const float gf = acc1[r] + bf2f((unsigned short)pj[r][1]);
                const float gg = acc2[r] + bf2f((unsigned short)pj[r][2]);
                const float go = acc3[r] + bf2f((unsigned short)pj[r][3]);
                const float iv = 1.f / (1.f + __expf(-gi));
                const float fv = 1.f / (1.f + __expf(-gf));
                const float gv = tanhf(gg);
                const float ov = 1.f / (1.f + __expf(-go));
                c[r] = fv * c[r] + iv * gv;
                Hlds[ksp * 512 + (row + 32 * khp) * 8 + jp] = f2bf(ov * tanhf(c[r]));
            }
        }
        __syncthreads();   // writes visible before next step's reads
    }

    // ---- final H -> global (hfrag layout == LDS layout per pos-tile)
    unsigned short* ho = hfin + (size_t)chain * (NPOS * HH) + (size_t)pt * 12288;
    ((int4*)ho)[tid] = ((const int4*)Hlds)[tid];
    ((int4*)ho)[tid + 768] = ((const int4*)Hlds)[tid + 768];
}

// ---------------------------------------------------------------- attention + linear head
static __device__ __forceinline__ float hfrag_get(const unsigned short* __restrict__ h,
                                                  int chain, int P, int c) {
    const size_t idx = (size_t)chain * (NPOS * HH)
        + (size_t)((P >> 5) * 24 + (c >> 4)) * 512
        + ((P & 31) + 32 * ((c >> 3) & 1)) * 8 + (c & 7);
    return bf2f(h[idx]);
}

__global__ __launch_bounds__(256) void attn_out_kernel(
        const float* __restrict__ x, const unsigned short* __restrict__ hout,
        const float* __restrict__ lin_w, const float* __restrict__ lin_b,
        float* __restrict__ out) {
    const int P = blockIdx.x;
    const int tid = threadIdx.x;
    const int lane = tid & 63, wid = tid >> 6;
    __shared__ float sc[NWIN][4];
    __shared__ float attn_s[NWIN];
    __shared__ float ov[DD];
    __shared__ float red[NLIN][4];
    const float inv_sqrt_d = 0.03608439182435161f;

    float xr[3];
#pragma unroll
    for (int j = 0; j < 3; ++j) xr[j] = x[(size_t)P * DD + tid + 256 * j];

#pragma unroll
    for (int wi = 0; wi < NWIN; ++wi) {
        float part = 0.f;
#pragma unroll
        for (int j = 0; j < 3; ++j) {
            const int col = tid + 256 * j;
            const float m = (col < HH) ? hfrag_get(hout, wi, P, col)
                                       : hfrag_get(hout, 4 + wi, P, col - HH);
            part = fmaf(xr[j], m, part);
        }
        for (int off = 32; off > 0; off >>= 1) part += __shfl_down(part, off);
        if (lane == 0) sc[wi][wid] = part;
    }
    __syncthreads();
    if (tid == 0) {
        float s[NWIN], mx = -1e30f;
        for (int wi = 0; wi < NWIN; ++wi) {
            s[wi] = (sc[wi][0] + sc[wi][1] + sc[wi][2] + sc[wi][3]) * inv_sqrt_d;
            mx = fmaxf(mx, s[wi]);
        }
        float denom = 0.f;
        for (int wi = 0; wi < NWIN; ++wi) { s[wi] = __expf(s[wi] - mx); denom += s[wi]; }
        for (int wi = 0; wi < NWIN; ++wi) attn_s[wi] = s[wi] / denom;
    }
    __syncthreads();
#pragma unroll
    for (int j = 0; j < 3; ++j) {
        const int col = tid + 256 * j;
        float lv = 0.f;
#pragma unroll
        for (int wi = 0; wi < NWIN; ++wi) {
            const float m = (col < HH) ? hfrag_get(hout, wi, P, col)
                                       : hfrag_get(hout, 4 + wi, P, col - HH);
            lv = fmaf(attn_s[wi], m, lv);
        }
        ov[col] = xr[j] + lv;
    }
    __syncthreads();
    for (int r = 0; r < NLIN; ++r) {
        float part = 0.f;
#pragma unroll
        for (int j = 0; j < 3; ++j) {
            const int col = tid + 256 * j;
            part = fmaf(ov[col], lin_w[r * DD + col], part);
        }
        for (int off = 32; off > 0; off >>= 1) part += __shfl_down(part, off);
        if (lane == 0) red[r][wid] = part;
    }
    __syncthreads();
    if (tid < NLIN)
        out[(size_t)P * NLIN + tid] = red[tid][0] + red[tid][1] + red[tid][2] + red[tid][3] + lin_b[tid];
}

// ---------------------------------------------------------------- launch
extern "C" void kernel_launch(void* const* d_in, const int* in_sizes, int n_in,
                              void* d_out, int out_size, void* d_ws, size_t ws_size,
                              hipStream_t stream) {
    (void)in_sizes; (void)n_in; (void)out_size; (void)ws_size;
    const float* seq   = (const float*)d_in[0];
    const int*   valid = (const int*)d_in[1];
    const float* wih_f = (const float*)d_in[2];
    const float* whh_f = (const float*)d_in[3];
    const float* bih_f = (const float*)d_in[4];
    const float* bhh_f = (const float*)d_in[5];
    const float* wih_b = (const float*)d_in[6];
    const float* whh_b = (const float*)d_in[7];
    const float* bih_b = (const float*)d_in[8];
    const float* bhh_b = (const float*)d_in[9];
    const float* lin_w = (const float*)d_in[10];
    const float* lin_b = (const float*)d_in[11];
    float* out = (float*)d_out;

    // workspace layout (~63 MB)
    float*          x     = (float*)d_ws;                          // 786432 f32
    unsigned short* xfrag = (unsigned short*)(x + NPOS * DD);      // 786432 bf16
    unsigned short* proj  = xfrag + (size_t)NPOS * DD;             // 12582912 bf16
    unsigned short* wfhh  = proj + (size_t)NPOS * PROJ_N;          // 4718592 bf16
    unsigned short* wfih  = wfhh + (size_t)4718592;                // 9437184 bf16
    unsigned short* hfin  = wfih + (size_t)9437184;                // 3145728 bf16
    float*          bias  = (float*)(hfin + (size_t)8 * NPOS * HH);// 12288 f32

    // x + xfrag contiguous: one zero launch (4718592 B = 294912 float4)
    zero_f4<<<(294912 + 255) / 256, 256, 0, stream>>>((float4*)x, 294912);
    scatter_kernel<<<128, 256, 0, stream>>>(seq, valid, x, xfrag);
    cast_frag<<<384, 256, 0, stream>>>(wih_f, wih_b, wfih, DD);
    cast_frag<<<384, 256, 0, stream>>>(whh_f, whh_b, wfhh, HH);
    bias_kernel<<<48, 256, 0, stream>>>(bih_f, bhh_f, bih_b, bhh_b, bias);
    proj_mfma<<<768, 256, 0, stream>>>(xfrag, wfih, bias, proj);
    lstm_fused<<<256, 768, 0, stream>>>(wfhh, proj, hfin);
    attn_out_kernel<<<NPOS, 256, 0, stream>>>(x, hfin, lin_w, lin_b, out);
}

// Round 7
// 319.530 us; speedup vs baseline: 2.1179x; 1.1896x over previous
//
#include <hip/hip_runtime.h>
#include <math.h>

#define LL 256
#define DD 768
#define HH 384
#define G4 1536
#define NWIN 4
#define NLIN 9
#define NPOS 1024        // B*L
#define PROJ_N 12288     // 8 chains * 1536

typedef __attribute__((ext_vector_type(8))) short short8;
typedef __attribute__((ext_vector_type(4))) short short4v;
typedef __attribute__((ext_vector_type(16))) float f32x16;

static __device__ __forceinline__ float bf2f(unsigned short u) {
    union { unsigned int i; float f; } v; v.i = ((unsigned int)u) << 16; return v.f;
}
static __device__ __forceinline__ unsigned short f2bf(float f) {
    unsigned int u = __float_as_uint(f);
    u += 0x7fff + ((u >> 16) & 1);   // round-to-nearest-even
    return (unsigned short)(u >> 16);
}
// fast sigmoid/tanh: v_exp_f32 + v_rcp_f32 (exact at +-inf, ~1e-6 rel err)
static __device__ __forceinline__ float fsig(float x) {
    return __builtin_amdgcn_rcpf(1.f + __expf(-x));
}
static __device__ __forceinline__ float ftanh(float x) {
    return 1.f - 2.f * __builtin_amdgcn_rcpf(1.f + __expf(2.f * x));
}

// ---------------------------------------------------------------- zero
__global__ void zero_f4(float4* __restrict__ p, int n4) {
    int i = blockIdx.x * blockDim.x + threadIdx.x;
    if (i < n4) p[i] = make_float4(0.f, 0.f, 0.f, 0.f);
}

// ---------------------------------------------------------------- scatter
__global__ void scatter_kernel(const float* __restrict__ seq,
                               const int* __restrict__ valid,
                               float* __restrict__ x,
                               unsigned short* __restrict__ xfrag) {
    const int b = blockIdx.x >> 5;
    const int chunk = blockIdx.x & 31;
    const int tid = threadIdx.x;
    __shared__ int vbuf[LL];
    __shared__ int dest[LL];
    vbuf[tid] = valid[b * LL + tid];
    __syncthreads();
    if (tid == 0) {
        int c = 0;
        for (int l = 0; l < LL; ++l) dest[l] = vbuf[l] ? c++ : -1;
    }
    __syncthreads();
    for (int l = chunk * 8; l < chunk * 8 + 8; ++l) {
        const int d = dest[l];
        if (d >= 0) {
            const float* src = seq + (size_t)(b * LL + l) * DD;
            float* dst = x + (size_t)(b * LL + d) * DD;
            for (int j = tid; j < DD / 4; j += 256)
                ((float4*)dst)[j] = ((const float4*)src)[j];
            const int pos = b * LL + d;
            const int pt = pos >> 5, pl = pos & 31;
            for (int j = tid; j < DD / 8; j += 256) {
                const float4 v0 = ((const float4*)src)[2 * j];
                const float4 v1 = ((const float4*)src)[2 * j + 1];
                short8 pv;
                pv[0] = (short)f2bf(v0.x); pv[1] = (short)f2bf(v0.y);
                pv[2] = (short)f2bf(v0.z); pv[3] = (short)f2bf(v0.w);
                pv[4] = (short)f2bf(v1.x); pv[5] = (short)f2bf(v1.y);
                pv[6] = (short)f2bf(v1.z); pv[7] = (short)f2bf(v1.w);
                *(short8*)(xfrag + ((size_t)(pt * 48 + (j >> 1)) * 512 + (pl + 32 * (j & 1)) * 8)) = pv;
            }
        }
    }
}

// ---------------------------------------------------------------- cast weights -> B-fragment layout
__global__ __launch_bounds__(256) void cast_frag(
        const float* __restrict__ srcF, const float* __restrict__ srcB,
        unsigned short* __restrict__ dst, int K) {
    __shared__ unsigned short lds[32 * 768];
    const int tid = threadIdx.x;
    const int vrow0 = blockIdx.x * 32;
    const int chain = vrow0 / G4;
    const int dir = chain >> 2, wi = chain & 3;
    const float* src = (dir ? srcB : srcF) + (size_t)(wi * G4 + (vrow0 % G4)) * K;
    const int total = 32 * K;
    for (int i = tid * 4; i < total; i += 1024) {
        const float4 v = *(const float4*)(src + i);
        lds[i + 0] = f2bf(v.x); lds[i + 1] = f2bf(v.y);
        lds[i + 2] = f2bf(v.z); lds[i + 3] = f2bf(v.w);
    }
    __syncthreads();
    const int nks = K >> 4;
    for (int slot = tid; slot < nks * 64; slot += 256) {
        const int ks = slot >> 6;
        const int lane = slot & 63;
        const int row = lane & 31;
        const int kb = ks * 16 + (lane >> 5) * 8;
        const short8 v = *(const short8*)&lds[row * K + kb];
        *(short8*)(dst + ((size_t)blockIdx.x * nks + ks) * 512 + lane * 8) = v;
    }
}

// ---------------------------------------------------------------- combined bias
__global__ void bias_kernel(const float* __restrict__ bihf, const float* __restrict__ bhhf,
                            const float* __restrict__ bihb, const float* __restrict__ bhhb,
                            float* __restrict__ bias) {
    const int n = blockIdx.x * 256 + threadIdx.x;
    if (n >= PROJ_N) return;
    const int chain = n / G4, r = n % G4;
    const int dir = chain >> 2, wi = chain & 3;
    bias[n] = (dir ? bihb : bihf)[wi * G4 + r] + (dir ? bhhb : bhhf)[wi * G4 + r];
}

// ---------------------------------------------------------------- proj GEMM (MFMA)
// Block = (chain, us, mtg): 4 waves = 4 gates (share B per iter), each wave
// computes 4 mt tiles (32 pos each) for its gate over K=768.
// Output proj[pos][chain][u][gate] via LDS staging -> dense 256B/row stores.
__global__ __launch_bounds__(256) void proj_mfma(
        const unsigned short* __restrict__ xf,
        const unsigned short* __restrict__ wf,
        const float* __restrict__ bias,
        unsigned short* __restrict__ proj) {
    __shared__ __align__(16) unsigned short st[4 * 4096];   // 32 KB
    const int wv = threadIdx.x >> 6;        // gate
    const int lane = threadIdx.x & 63;
    const int colid = lane & 31, hq = lane >> 5;
    const int mtg = blockIdx.x & 7;
    const int cu = blockIdx.x >> 3;         // 0..95
    const int chain = cu / 12;
    const int us = cu % 12;

    const unsigned short* bP = wf + (size_t)((chain * 48 + wv * 12 + us) * 48) * 512 + lane * 8;
    const unsigned short* aP = xf + (size_t)(mtg * 4 * 48) * 512 + lane * 8;

    f32x16 acc[4] = {};
#pragma unroll 4
    for (int ks = 0; ks < 48; ++ks) {
        const short8 bv = *(const short8*)(bP + ks * 512);
        const short8 a0 = *(const short8*)(aP + (0 * 48 + ks) * 512);
        const short8 a1 = *(const short8*)(aP + (1 * 48 + ks) * 512);
        const short8 a2 = *(const short8*)(aP + (2 * 48 + ks) * 512);
        const short8 a3 = *(const short8*)(aP + (3 * 48 + ks) * 512);
        acc[0] = __builtin_amdgcn_mfma_f32_32x32x16_bf16(a0, bv, acc[0], 0, 0, 0);
        acc[1] = __builtin_amdgcn_mfma_f32_32x32x16_bf16(a1, bv, acc[1], 0, 0, 0);
        acc[2] = __builtin_amdgcn_mfma_f32_32x32x16_bf16(a2, bv, acc[2], 0, 0, 0);
        acc[3] = __builtin_amdgcn_mfma_f32_32x32x16_bf16(a3, bv, acc[3], 0, 0, 0);
    }
    const float bv = bias[chain * G4 + wv * HH + us * 32 + colid];
#pragma unroll
    for (int i = 0; i < 4; ++i) {
#pragma unroll
        for (int r = 0; r < 16; ++r) {
            const int row = (r & 3) + 8 * (r >> 2) + 4 * hq;
            st[i * 4096 + (row * 32 + colid) * 4 + wv] = f2bf(acc[i][r] + bv);
        }
    }
    __syncthreads();
#pragma unroll
    for (int j = 0; j < 8; ++j) {
        const int idx = j * 256 + threadIdx.x;    // 0..2047 int4
        const int i = idx >> 9, rem = idx & 511;
        const int pl = rem >> 4, q = rem & 15;
        const int pos = (mtg * 4 + i) * 32 + pl;
        *(int4*)(proj + (size_t)pos * PROJ_N + chain * G4 + us * 128 + q * 8) =
            ((const int4*)st)[idx];
    }
}

// ---------------------------------------------------------------- fused LSTM recurrence
// One block per (chain, 32-pos tile); 256 blocks = 1/CU; 768 thr = 12 waves.
// Chain-pair XCD mapping balances per-XCD L2 W-traffic (2.4MB < 4MB L2).
// H in LDS (A-frag layout), C in regs, proj gate-packed; fast exp/rcp gates.
__global__ __launch_bounds__(768, 3) void lstm_fused(
        const unsigned short* __restrict__ Wf,
        const unsigned short* __restrict__ proj,
        unsigned short* __restrict__ hfin) {
    const int p = blockIdx.x & 3, sub = (blockIdx.x >> 2) & 1;
    const int slot = blockIdx.x >> 3;
    const int chainA[4] = {3, 7, 2, 6};   // w=9,9,7,7
    const int chainB[4] = {0, 4, 1, 5};   // w=3,3,5,5
    const int chain = (slot < 16) ? chainA[p] : chainB[p];
    const int pt = sub * 16 + (slot & 15);
    const int dir = chain >> 2, wi = chain & 3;
    const int w = 3 + 2 * wi, half = wi + 1;
    const int tid = threadIdx.x;
    const int lane = tid & 63, wv = tid >> 6;   // wv 0..11 = unit slice
    const int colid = lane & 31, hq = lane >> 5;
    const int uu = wv * 32 + colid;
    const int m0 = pt * 32, b = m0 >> 8, l0 = m0 & 255;

    __shared__ __align__(16) unsigned short Hlds[24 * 512];   // 24 KB
    ((int4*)Hlds)[tid] = make_int4(0, 0, 0, 0);
    ((int4*)Hlds)[tid + 768] = make_int4(0, 0, 0, 0);
    float c[16];
#pragma unroll
    for (int r = 0; r < 16; ++r) c[r] = 0.f;

    // per-r fixed source base (src = sb[r] + t, then clamp)
    int sb[16];
#pragma unroll
    for (int r = 0; r < 16; ++r) {
        const int row = (r & 3) + 8 * (r >> 2) + 4 * hq;
        sb[r] = l0 + row - half;
    }

    const unsigned short* projb = proj + (size_t)(b * LL) * PROJ_N + chain * G4 + uu * 4;
    const unsigned short* Wb = Wf + (size_t)((chain * 48 + wv) * 24) * 512 + lane * 8;
    const unsigned short* Alds = Hlds + lane * 8;
    const int ksp = uu >> 4, khp = (uu >> 3) & 1, jp = uu & 7;

    __syncthreads();

    for (int s = 0; s < w; ++s) {
        const int t = dir ? (w - 1 - s) : s;
        // ---- gate-packed proj prefetch (independent of MFMAs, 32-bit addr)
        short4v pj[16];
#pragma unroll
        for (int r = 0; r < 16; ++r) {
            int src = sb[r] + t;
            src = src < 0 ? 0 : (src > LL - 1 ? LL - 1 : src);
            pj[r] = *(const short4v*)(projb + src * PROJ_N);
        }
        f32x16 acc0 = {}, acc1 = {}, acc2 = {}, acc3 = {};
        if (s > 0) {   // s==0: H is zero, gates = proj only
#pragma unroll 4
            for (int ks = 0; ks < 24; ++ks) {
                const short8 av  = *(const short8*)(Alds + ks * 512);
                const short8 bv0 = *(const short8*)(Wb + (size_t)(0 * 288 + ks) * 512);
                const short8 bv1 = *(const short8*)(Wb + (size_t)(1 * 288 + ks) * 512);
                const short8 bv2 = *(const short8*)(Wb + (size_t)(2 * 288 + ks) * 512);
                const short8 bv3 = *(const short8*)(Wb + (size_t)(3 * 288 + ks) * 512);
                acc0 = __builtin_amdgcn_mfma_f32_32x32x16_bf16(av, bv0, acc0, 0, 0, 0);
                acc1 = __builtin_amdgcn_mfma_f32_32x32x16_bf16(av, bv1, acc1, 0, 0, 0);
                acc2 = __builtin_amdgcn_mfma_f32_32x32x16_bf16(av, bv2, acc2, 0, 0, 0);
                acc3 = __builtin_amdgcn_mfma_f32_32x32x16_bf16(av, bv3, acc3, 0, 0, 0);
            }
        }
        __syncthreads();   // all LDS reads of step s done

#pragma unroll
        for (int r = 0; r < 16; ++r) {
            const int row = (r & 3) + 8 * (r >> 2) + 4 * hq;
            const int src = sb[r] + t;
            if (src >= 0 && src < LL) {
                const float gi = acc0[r] + bf2f((unsigned short)pj[r][0]);
                const float gf = acc1[r] + bf2f((unsigned short)pj[r][1]);
                const float gg = acc2[r] + bf2f((unsigned short)pj[r][2]);
                const float go = acc3[r] + bf2f((unsigned short)pj[r][3]);
                c[r] = fsig(gf) * c[r] + fsig(gi) * ftanh(gg);
                Hlds[ksp * 512 + (row + 32 * khp) * 8 + jp] = f2bf(fsig(go) * ftanh(c[r]));
            }
        }
        __syncthreads();   // writes visible before next step's reads
    }

    // ---- final H -> global (hfrag layout == LDS layout per pos-tile)
    unsigned short* ho = hfin + (size_t)chain * (NPOS * HH) + (size_t)pt * 12288;
    ((int4*)ho)[tid] = ((const int4*)Hlds)[tid];
    ((int4*)ho)[tid + 768] = ((const int4*)Hlds)[tid + 768];
}

// ---------------------------------------------------------------- attention + linear head
static __device__ __forceinline__ float hfrag_get(const unsigned short* __restrict__ h,
                                                  int chain, int P, int c) {
    const size_t idx = (size_t)chain * (NPOS * HH)
        + (size_t)((P >> 5) * 24 + (c >> 4)) * 512
        + ((P & 31) + 32 * ((c >> 3) & 1)) * 8 + (c & 7);
    return bf2f(h[idx]);
}

__global__ __launch_bounds__(256) void attn_out_kernel(
        const float* __restrict__ x, const unsigned short* __restrict__ hout,
        const float* __restrict__ lin_w, const float* __restrict__ lin_b,
        float* __restrict__ out) {
    const int P = blockIdx.x;
    const int tid = threadIdx.x;
    const int lane = tid & 63, wid = tid >> 6;
    __shared__ float sc[NWIN][4];
    __shared__ float attn_s[NWIN];
    __shared__ float ov[DD];
    __shared__ float red[NLIN][4];
    const float inv_sqrt_d = 0.03608439182435161f;

    float xr[3];
#pragma unroll
    for (int j = 0; j < 3; ++j) xr[j] = x[(size_t)P * DD + tid + 256 * j];

#pragma unroll
    for (int wi = 0; wi < NWIN; ++wi) {
        float part = 0.f;
#pragma unroll
        for (int j = 0; j < 3; ++j) {
            const int col = tid + 256 * j;
            const float m = (col < HH) ? hfrag_get(hout, wi, P, col)
                                       : hfrag_get(hout, 4 + wi, P, col - HH);
            part = fmaf(xr[j], m, part);
        }
        for (int off = 32; off > 0; off >>= 1) part += __shfl_down(part, off);
        if (lane == 0) sc[wi][wid] = part;
    }
    __syncthreads();
    if (tid == 0) {
        float s[NWIN], mx = -1e30f;
        for (int wi = 0; wi < NWIN; ++wi) {
            s[wi] = (sc[wi][0] + sc[wi][1] + sc[wi][2] + sc[wi][3]) * inv_sqrt_d;
            mx = fmaxf(mx, s[wi]);
        }
        float denom = 0.f;
        for (int wi = 0; wi < NWIN; ++wi) { s[wi] = __expf(s[wi] - mx); denom += s[wi]; }
        for (int wi = 0; wi < NWIN; ++wi) attn_s[wi] = s[wi] / denom;
    }
    __syncthreads();
#pragma unroll
    for (int j = 0; j < 3; ++j) {
        const int col = tid + 256 * j;
        float lv = 0.f;
#pragma unroll
        for (int wi = 0; wi < NWIN; ++wi) {
            const float m = (col < HH) ? hfrag_get(hout, wi, P, col)
                                       : hfrag_get(hout, 4 + wi, P, col - HH);
            lv = fmaf(attn_s[wi], m, lv);
        }
        ov[col] = xr[j] + lv;
    }
    __syncthreads();
    for (int r = 0; r < NLIN; ++r) {
        float part = 0.f;
#pragma unroll
        for (int j = 0; j < 3; ++j) {
            const int col = tid + 256 * j;
            part = fmaf(ov[col], lin_w[r * DD + col], part);
        }
        for (int off = 32; off > 0; off >>= 1) part += __shfl_down(part, off);
        if (lane == 0) red[r][wid] = part;
    }
    __syncthreads();
    if (tid < NLIN)
        out[(size_t)P * NLIN + tid] = red[tid][0] + red[tid][1] + red[tid][2] + red[tid][3] + lin_b[tid];
}

// ---------------------------------------------------------------- launch
extern "C" void kernel_launch(void* const* d_in, const int* in_sizes, int n_in,
                              void* d_out, int out_size, void* d_ws, size_t ws_size,
                              hipStream_t stream) {
    (void)in_sizes; (void)n_in; (void)out_size; (void)ws_size;
    const float* seq   = (const float*)d_in[0];
    const int*   valid = (const int*)d_in[1];
    const float* wih_f = (const float*)d_in[2];
    const float* whh_f = (const float*)d_in[3];
    const float* bih_f = (const float*)d_in[4];
    const float* bhh_f = (const float*)d_in[5];
    const float* wih_b = (const float*)d_in[6];
    const float* whh_b = (const float*)d_in[7];
    const float* bih_b = (const float*)d_in[8];
    const float* bhh_b = (const float*)d_in[9];
    const float* lin_w = (const float*)d_in[10];
    const float* lin_b = (const float*)d_in[11];
    float* out = (float*)d_out;

    // workspace layout (~63 MB)
    float*          x     = (float*)d_ws;                          // 786432 f32
    unsigned short* xfrag = (unsigned short*)(x + NPOS * DD);      // 786432 bf16
    unsigned short* proj  = xfrag + (size_t)NPOS * DD;             // 12582912 bf16
    unsigned short* wfhh  = proj + (size_t)NPOS * PROJ_N;          // 4718592 bf16
    unsigned short* wfih  = wfhh + (size_t)4718592;                // 9437184 bf16
    unsigned short* hfin  = wfih + (size_t)9437184;                // 3145728 bf16
    float*          bias  = (float*)(hfin + (size_t)8 * NPOS * HH);// 12288 f32

    // x + xfrag contiguous: one zero launch (4718592 B = 294912 float4)
    zero_f4<<<(294912 + 255) / 256, 256, 0, stream>>>((float4*)x, 294912);
    scatter_kernel<<<128, 256, 0, stream>>>(seq, valid, x, xfrag);
    cast_frag<<<384, 256, 0, stream>>>(wih_f, wih_b, wfih, DD);
    cast_frag<<<384, 256, 0, stream>>>(whh_f, whh_b, wfhh, HH);
    bias_kernel<<<48, 256, 0, stream>>>(bih_f, bhh_f, bih_b, bhh_b, bias);
    proj_mfma<<<768, 256, 0, stream>>>(xfrag, wfih, bias, proj);
    lstm_fused<<<256, 768, 0, stream>>>(wfhh, proj, hfin);
    attn_out_kernel<<<NPOS, 256, 0, stream>>>(x, hfin, lin_w, lin_b, out);
}